// Round 5
// baseline (389.605 us; speedup 1.0000x reference)
//
#include <hip/hip_runtime.h>
#include <utility>

// Problem constants: N=262144 rows, NX=NQ=64, NU=16, fp32.
#define NROWS 262144
#define T 256

typedef float f16v __attribute__((ext_vector_type(16)));
#define LD16(p) (*(const f16v*)(p))

// d_ws layout (floats):
//   AT   [4096]  @ 0      : AT[j*64+k]  = A[k][j]
//   C1T  [4096]  @ 4096   : C1T[j*64+i] = C1[i][j]
//   D11T [4096]  @ 8192   : D11T[i*64+k]= D11[k][i]   (col i of D11; 0 for k<=i)
//   B1T  [4096]  @ 12288  : B1T[i*64+k] = B1[k][i]
//   B2T  [1024]  @ 16384  : B2T[j*64+k] = B2[k][j]
//   D12T [1024]  @ 17408  : D12T[j*64+i]= D12[i][j]
//   bv   [64]    @ 18432
//   bx   [64]    @ 18496

__global__ void prep_kernel(const float* __restrict__ A, const float* __restrict__ B1,
                            const float* __restrict__ B2, const float* __restrict__ C1,
                            const float* __restrict__ D11, const float* __restrict__ D12,
                            const float* __restrict__ bv, const float* __restrict__ bx,
                            float* __restrict__ ws) {
    int g = blockIdx.x * 256 + threadIdx.x;
    if (g < 4096) {
        int r = g >> 6, c = g & 63;
        int to = c * 64 + r;
        ws[0 * 4096 + to] = A[g];
        ws[1 * 4096 + to] = C1[g];
        ws[2 * 4096 + to] = D11[g];
        ws[3 * 4096 + to] = B1[g];
    }
    if (g < 1024) {
        int r = g >> 4, c = g & 15;   // 64x16 row-major in
        int to = c * 64 + r;
        ws[16384 + to] = B2[g];
        ws[17408 + to] = D12[g];
    }
    if (g < 64) {
        ws[18432 + g] = bv[g];
        ws[18496 + g] = bx[g];
    }
}

// ---- substitution step I: finalize w_I = relu(s_I), scatter D11 column I
// (from LDS, broadcast) into rows > I.
template<int I>
__device__ __forceinline__ void substep(f16v& s0, f16v& s1, f16v& s2, f16v& s3,
                                        const float* D11s) {
    constexpr int vi = I >> 4, e = I & 15;
    float v;
    if constexpr (vi == 0) v = s0[e];
    else if constexpr (vi == 1) v = s1[e];
    else if constexpr (vi == 2) v = s2[e];
    else v = s3[e];
    const float wv = fmaxf(v, 0.0f);
    if constexpr (vi == 0) s0[e] = wv;
    else if constexpr (vi == 1) s1[e] = wv;
    else if constexpr (vi == 2) s2[e] = wv;
    else s3[e] = wv;
    const float* col = D11s + I * 64;
    if constexpr (I < 15) s0 += LD16(col) * wv;
    if constexpr (I < 31) s1 += LD16(col + 16) * wv;
    if constexpr (I < 47) s2 += LD16(col + 32) * wv;
    if constexpr (I < 63) s3 += LD16(col + 48) * wv;
}

template<int... Is>
__device__ __forceinline__ void subst_all(f16v& s0, f16v& s1, f16v& s2, f16v& s3,
                                          const float* D11s,
                                          std::integer_sequence<int, Is...>) {
    (substep<Is>(s0, s1, s2, s3, D11s), ...);
}

// ---- Kernel A: w = forward_subst(bv + C1 x + D12 u) -> wout (= d_out).
// Matrices staged in LDS (broadcast ds_read), state in named f16v SSA values.
__global__ __launch_bounds__(T, 4) void w_kernel(const float* __restrict__ x,
                                                 const float* __restrict__ u,
                                                 const float* __restrict__ ws,
                                                 float* __restrict__ wout) {
    // LDS: C1T @0 [4096], D11T @4096 [4096], D12T @8192 [1024], bv @9216 [64]
    __shared__ float sm[9280];
    const int tid = threadIdx.x;
#pragma unroll 4
    for (int i = tid; i < 4096; i += T) {
        sm[i]        = ws[4096 + i];   // C1T
        sm[4096 + i] = ws[8192 + i];   // D11T
    }
#pragma unroll 2
    for (int i = tid; i < 1024; i += T) sm[8192 + i] = ws[17408 + i];  // D12T
    if (tid < 64) sm[9216 + tid] = ws[18432 + tid];                    // bv
    __syncthreads();

    const float* C1s  = sm;
    const float* D11s = sm + 4096;
    const float* D12s = sm + 8192;
    const float* bvs  = sm + 9216;

    const int n = blockIdx.x * T + tid;
    const float* __restrict__ xr = x + (size_t)n * 64;
    const float* __restrict__ ur = u + (size_t)n * 16;

    f16v s0 = LD16(bvs), s1 = LD16(bvs + 16), s2 = LD16(bvs + 32), s3 = LD16(bvs + 48);

#pragma unroll 1
    for (int j = 0; j < 64; j += 4) {
        const float4 xv = *(const float4*)(xr + j);
#pragma unroll
        for (int jj = 0; jj < 4; jj++) {
            const float xs = (jj == 0) ? xv.x : (jj == 1) ? xv.y : (jj == 2) ? xv.z : xv.w;
            const float* cc = C1s + (j + jj) * 64;
            s0 += LD16(cc) * xs; s1 += LD16(cc + 16) * xs;
            s2 += LD16(cc + 32) * xs; s3 += LD16(cc + 48) * xs;
        }
    }
#pragma unroll 1
    for (int j = 0; j < 16; j += 4) {
        const float4 uv = *(const float4*)(ur + j);
#pragma unroll
        for (int jj = 0; jj < 4; jj++) {
            const float us = (jj == 0) ? uv.x : (jj == 1) ? uv.y : (jj == 2) ? uv.z : uv.w;
            const float* dc = D12s + (j + jj) * 64;
            s0 += LD16(dc) * us; s1 += LD16(dc + 16) * us;
            s2 += LD16(dc + 32) * us; s3 += LD16(dc + 48) * us;
        }
    }

    subst_all(s0, s1, s2, s3, D11s, std::make_integer_sequence<int, 64>{});

    float* op = wout + (size_t)n * 64;
    *(f16v*)(op) = s0; *(f16v*)(op + 16) = s1;
    *(f16v*)(op + 32) = s2; *(f16v*)(op + 48) = s3;
}

// ---- Kernel B: out = bx + A x + B2 u + B1 w. Reads w from wo (= d_out) and
// overwrites the same row (same-thread RAW -> safe).
__global__ __launch_bounds__(T, 4) void out_kernel(const float* __restrict__ x,
                                                   const float* __restrict__ u,
                                                   const float* __restrict__ ws,
                                                   float* wo) {
    // LDS: AT @0 [4096], B1T @4096 [4096], B2T @8192 [1024], bx @9216 [64]
    __shared__ float sm[9280];
    const int tid = threadIdx.x;
#pragma unroll 4
    for (int i = tid; i < 4096; i += T) {
        sm[i]        = ws[i];           // AT
        sm[4096 + i] = ws[12288 + i];   // B1T
    }
#pragma unroll 2
    for (int i = tid; i < 1024; i += T) sm[8192 + i] = ws[16384 + i];  // B2T
    if (tid < 64) sm[9216 + tid] = ws[18496 + tid];                    // bx
    __syncthreads();

    const float* As  = sm;
    const float* B1s = sm + 4096;
    const float* B2s = sm + 8192;
    const float* bxs = sm + 9216;

    const int n = blockIdx.x * T + tid;
    const float* __restrict__ xr = x + (size_t)n * 64;
    const float* __restrict__ ur = u + (size_t)n * 16;
    float* wr = wo + (size_t)n * 64;

    f16v a0 = LD16(bxs), a1 = LD16(bxs + 16), a2 = LD16(bxs + 32), a3 = LD16(bxs + 48);

#pragma unroll 1
    for (int j = 0; j < 64; j += 4) {
        const float4 xv = *(const float4*)(xr + j);
#pragma unroll
        for (int jj = 0; jj < 4; jj++) {
            const float xs = (jj == 0) ? xv.x : (jj == 1) ? xv.y : (jj == 2) ? xv.z : xv.w;
            const float* ac = As + (j + jj) * 64;
            a0 += LD16(ac) * xs; a1 += LD16(ac + 16) * xs;
            a2 += LD16(ac + 32) * xs; a3 += LD16(ac + 48) * xs;
        }
    }
#pragma unroll 1
    for (int j = 0; j < 16; j += 4) {
        const float4 uv = *(const float4*)(ur + j);
#pragma unroll
        for (int jj = 0; jj < 4; jj++) {
            const float us = (jj == 0) ? uv.x : (jj == 1) ? uv.y : (jj == 2) ? uv.z : uv.w;
            const float* bc = B2s + (j + jj) * 64;
            a0 += LD16(bc) * us; a1 += LD16(bc + 16) * us;
            a2 += LD16(bc + 32) * us; a3 += LD16(bc + 48) * us;
        }
    }
#pragma unroll 1
    for (int j = 0; j < 64; j += 4) {
        const float4 wv = *(const float4*)(wr + j);
#pragma unroll
        for (int jj = 0; jj < 4; jj++) {
            const float wsc = (jj == 0) ? wv.x : (jj == 1) ? wv.y : (jj == 2) ? wv.z : wv.w;
            const float* bc = B1s + (j + jj) * 64;
            a0 += LD16(bc) * wsc; a1 += LD16(bc + 16) * wsc;
            a2 += LD16(bc + 32) * wsc; a3 += LD16(bc + 48) * wsc;
        }
    }

    *(f16v*)(wr) = a0; *(f16v*)(wr + 16) = a1;
    *(f16v*)(wr + 32) = a2; *(f16v*)(wr + 48) = a3;
}

extern "C" void kernel_launch(void* const* d_in, const int* in_sizes, int n_in,
                              void* d_out, int out_size, void* d_ws, size_t ws_size,
                              hipStream_t stream) {
    const float* x   = (const float*)d_in[0];
    const float* u   = (const float*)d_in[1];
    const float* A   = (const float*)d_in[2];
    const float* B1  = (const float*)d_in[3];
    const float* B2  = (const float*)d_in[4];
    const float* C1  = (const float*)d_in[5];
    const float* D11 = (const float*)d_in[6];
    const float* D12 = (const float*)d_in[7];
    const float* bv  = (const float*)d_in[8];
    const float* bx  = (const float*)d_in[9];
    float* out = (float*)d_out;
    float* ws  = (float*)d_ws;

    prep_kernel<<<16, 256, 0, stream>>>(A, B1, B2, C1, D11, D12, bv, bx, ws);
    w_kernel<<<NROWS / T, T, 0, stream>>>(x, u, ws, out);     // w -> d_out
    out_kernel<<<NROWS / T, T, 0, stream>>>(x, u, ws, out);   // d_out -> x_dot
}

// Round 6
// 282.446 us; speedup vs baseline: 1.3794x; 1.3794x over previous
//
#include <hip/hip_runtime.h>
#include <utility>

// Problem constants: N=262144 rows, NX=NQ=64, NU=16, fp32.
#define NROWS 262144
#define BT 512                 // threads/block
#define RPB 128                // rows/block (= BT/4)

typedef float f16v __attribute__((ext_vector_type(16)));

// d_ws layout (floats) — two contiguous 9280-float phase blocks:
//  phase1 @0    : C1T[4096] | D11T[4096] | D12T[1024] | bv[64]
//  phase2 @9280 : AT [4096] | B1T [4096] | B2T [1024] | bx[64]
// In-block offsets (same for LDS): M0@0, M1@4096, M2@8192, bias@9216.
//  C1T[j*64+i]=C1[i][j]  D11T[i*64+k]=D11[k][i] (zeros at k<=i come from input)
//  D12T[j*64+i]=D12[i][j]  AT[j*64+k]=A[k][j]  B1T[i*64+k]=B1[k][i]
//  B2T[j*64+k]=B2[k][j]

__global__ void prep_kernel(const float* __restrict__ A, const float* __restrict__ B1,
                            const float* __restrict__ B2, const float* __restrict__ C1,
                            const float* __restrict__ D11, const float* __restrict__ D12,
                            const float* __restrict__ bv, const float* __restrict__ bx,
                            float* __restrict__ ws) {
    int g = blockIdx.x * 256 + threadIdx.x;
    if (g < 4096) {
        int r = g >> 6, c = g & 63;       // source row r, col c (64x64 row-major)
        int to = c * 64 + r;
        ws[0     + to] = C1[g];           // C1T
        ws[4096  + to] = D11[g];          // D11T
        ws[9280  + to] = A[g];            // AT
        ws[13376 + to] = B1[g];           // B1T
    }
    if (g < 1024) {
        int r = g >> 4, c = g & 15;       // 64x16 row-major source
        int to = c * 64 + r;
        ws[8192  + to] = D12[g];          // D12T
        ws[17472 + to] = B2[g];           // B2T
    }
    if (g < 64) {
        ws[9216  + g] = bv[g];
        ws[18496 + g] = bx[g];
    }
}

__device__ __forceinline__ f16v lds16(const float* p) { return *(const f16v*)p; }

// Substitution step I: quad-broadcast w_I from its owner lane via ds_swizzle
// (BitMode: keep lane bits[4:2], force bits[1:0] = I>>4), then uniform FMA —
// zeros in D11T column I make non-future entries exact no-ops.
template<int I>
__device__ __forceinline__ void substep(f16v& s, const float* D11s, int c16, int c) {
    const float v = s[I & 15];
    const int b = __builtin_amdgcn_ds_swizzle(__float_as_int(v), ((I >> 4) << 5) | 0x1C);
    const float wv = fmaxf(__int_as_float(b), 0.0f);
    s += lds16(D11s + I * 64 + c16) * wv;         // D11T[I][I]==0, safe for owner
    s[I & 15] = (c == (I >> 4)) ? wv : s[I & 15]; // owner finalizes its element
}

template<int... Is>
__device__ __forceinline__ void subst_all(f16v& s, const float* D11s, int c16, int c,
                                          std::integer_sequence<int, Is...>) {
    (substep<Is>(s, D11s, c16, c), ...);
}

// Fused kernel: quad (4 lanes) per row; each lane owns a 16-output chunk.
// Phase1: s = bv + C1 x + D12 u; substitution -> w; w tile -> d_out.
// (LDS overlay barrier drains vmcnt -> w globally visible to own block.)
// Phase2: out = bx + A x + B2 u + B1 w, overwriting the same d_out rows.
__global__ __launch_bounds__(BT, 4) void renl2_fused(const float* __restrict__ x,
                                                     const float* __restrict__ u,
                                                     const float* __restrict__ ws,
                                                     float* out /* no restrict: w RAW */) {
    __shared__ float sm[9280];            // 37.1 KB -> 4 blocks/CU
    const int tid = threadIdx.x;
    const int c   = tid & 3;              // quad chunk id
    const int c16 = c << 4;
    const int r   = tid >> 2;             // row within block
    const int row = blockIdx.x * RPB + r;

    const float* __restrict__ xr = x + (size_t)row * 64;
    const float* __restrict__ ur = u + (size_t)row * 16;
    float* wr = out + (size_t)row * 64;

    // ---- stage phase-1 matrices ----
#pragma unroll 4
    for (int i = tid; i < 9280; i += BT) sm[i] = ws[i];
    __syncthreads();

    // ---- phase 1: s = bv + C1 x + D12 u ----
    f16v s = lds16(sm + 9216 + c16);
#pragma unroll 1
    for (int j = 0; j < 64; j += 4) {
        const float4 xv = *(const float4*)(xr + j);
#pragma unroll
        for (int jj = 0; jj < 4; jj++) {
            const float xs = (jj == 0) ? xv.x : (jj == 1) ? xv.y : (jj == 2) ? xv.z : xv.w;
            s += lds16(sm + (j + jj) * 64 + c16) * xs;           // C1T @0
        }
    }
    {
        const float4 uv0 = *(const float4*)(ur);
        const float4 uv1 = *(const float4*)(ur + 4);
        const float4 uv2 = *(const float4*)(ur + 8);
        const float4 uv3 = *(const float4*)(ur + 12);
        const float us[16] = {uv0.x,uv0.y,uv0.z,uv0.w, uv1.x,uv1.y,uv1.z,uv1.w,
                              uv2.x,uv2.y,uv2.z,uv2.w, uv3.x,uv3.y,uv3.z,uv3.w};
#pragma unroll
        for (int j = 0; j < 16; j++)
            s += lds16(sm + 8192 + j * 64 + c16) * us[j];         // D12T @8192
    }

    // ---- substitution (intra-quad broadcast, branchless) ----
    subst_all(s, sm + 4096, c16, c, std::make_integer_sequence<int, 64>{});

    // ---- w chunk -> d_out ----
    *(float4*)(wr + c16)      = float4{s[0],  s[1],  s[2],  s[3]};
    *(float4*)(wr + c16 + 4)  = float4{s[4],  s[5],  s[6],  s[7]};
    *(float4*)(wr + c16 + 8)  = float4{s[8],  s[9],  s[10], s[11]};
    *(float4*)(wr + c16 + 12) = float4{s[12], s[13], s[14], s[15]};

    // ---- overlay phase-2 matrices (barriers drain vmcnt: w now visible) ----
    __syncthreads();
#pragma unroll 4
    for (int i = tid; i < 9280; i += BT) sm[i] = ws[9280 + i];
    __syncthreads();

    // ---- phase 2: acc = bx + A x + B2 u + B1 w ----
    f16v acc = lds16(sm + 9216 + c16);
#pragma unroll 1
    for (int j = 0; j < 64; j += 4) {
        const float4 xv = *(const float4*)(xr + j);
#pragma unroll
        for (int jj = 0; jj < 4; jj++) {
            const float xs = (jj == 0) ? xv.x : (jj == 1) ? xv.y : (jj == 2) ? xv.z : xv.w;
            acc += lds16(sm + (j + jj) * 64 + c16) * xs;          // AT @0
        }
    }
    {
        const float4 uv0 = *(const float4*)(ur);
        const float4 uv1 = *(const float4*)(ur + 4);
        const float4 uv2 = *(const float4*)(ur + 8);
        const float4 uv3 = *(const float4*)(ur + 12);
        const float us[16] = {uv0.x,uv0.y,uv0.z,uv0.w, uv1.x,uv1.y,uv1.z,uv1.w,
                              uv2.x,uv2.y,uv2.z,uv2.w, uv3.x,uv3.y,uv3.z,uv3.w};
#pragma unroll
        for (int j = 0; j < 16; j++)
            acc += lds16(sm + 8192 + j * 64 + c16) * us[j];       // B2T @8192
    }
#pragma unroll 1
    for (int j = 0; j < 64; j += 4) {
        const float4 wv = *(const float4*)(wr + j);               // w (quad-shared)
#pragma unroll
        for (int jj = 0; jj < 4; jj++) {
            const float wsc = (jj == 0) ? wv.x : (jj == 1) ? wv.y : (jj == 2) ? wv.z : wv.w;
            acc += lds16(sm + 4096 + (j + jj) * 64 + c16) * wsc;  // B1T @4096
        }
    }

    // ---- overwrite w with x_dot (same wave read w above: lockstep-safe) ----
    *(float4*)(wr + c16)      = float4{acc[0],  acc[1],  acc[2],  acc[3]};
    *(float4*)(wr + c16 + 4)  = float4{acc[4],  acc[5],  acc[6],  acc[7]};
    *(float4*)(wr + c16 + 8)  = float4{acc[8],  acc[9],  acc[10], acc[11]};
    *(float4*)(wr + c16 + 12) = float4{acc[12], acc[13], acc[14], acc[15]};
}

extern "C" void kernel_launch(void* const* d_in, const int* in_sizes, int n_in,
                              void* d_out, int out_size, void* d_ws, size_t ws_size,
                              hipStream_t stream) {
    const float* x   = (const float*)d_in[0];
    const float* u   = (const float*)d_in[1];
    const float* A   = (const float*)d_in[2];
    const float* B1  = (const float*)d_in[3];
    const float* B2  = (const float*)d_in[4];
    const float* C1  = (const float*)d_in[5];
    const float* D11 = (const float*)d_in[6];
    const float* D12 = (const float*)d_in[7];
    const float* bv  = (const float*)d_in[8];
    const float* bx  = (const float*)d_in[9];
    float* out = (float*)d_out;
    float* ws  = (float*)d_ws;

    prep_kernel<<<16, 256, 0, stream>>>(A, B1, B2, C1, D11, D12, bv, bx, ws);
    renl2_fused<<<NROWS / RPB, BT, 0, stream>>>(x, u, ws, out);
}